// Round 12
// baseline (96.398 us; speedup 1.0000x reference)
//
#include <hip/hip_runtime.h>

#define B_ 2
#define S_ 2048
#define H_ 16
#define DQ_ 192
#define DV_ 128
// log2(e)/sqrt(192): folded into Q at hoist time
#define SCL2 0.10411163731422901f

typedef short short8 __attribute__((ext_vector_type(8)));
typedef float f32x4 __attribute__((ext_vector_type(4)));
typedef float f32x16 __attribute__((ext_vector_type(16)));
typedef unsigned uint2v __attribute__((ext_vector_type(2)));

#define KG_BYTES ((size_t)25165824)   // B*H*S*DQ*2
#define VG_BYTES ((size_t)16777216)   // B*H*DV*S*2

__device__ __forceinline__ unsigned short f2bf(float f) {
  union { float f; unsigned u; } x; x.f = f;
  unsigned r = x.u + 0x7FFFu + ((x.u >> 16) & 1u);   // RNE
  return (unsigned short)(r >> 16);
}

__device__ __forceinline__ float hw_exp2(float x) {
  float r; asm("v_exp_f32 %0, %1" : "=v"(r) : "v"(x)); return r;
}
__device__ __forceinline__ unsigned cvtpk(float lo, float hi) {
  unsigned r; asm("v_cvt_pk_bf16_f32 %0, %1, %2" : "=v"(r) : "v"(lo), "v"(hi)); return r;
}
__device__ __forceinline__ float pl32max(float x) {
  uint2v r = __builtin_amdgcn_permlane32_swap(__float_as_uint(x), __float_as_uint(x), false, false);
  return fmaxf(__uint_as_float(r[0]), __uint_as_float(r[1]));
}
__device__ __forceinline__ float pl32add(float x) {
  uint2v r = __builtin_amdgcn_permlane32_swap(__float_as_uint(x), __float_as_uint(x), false, false);
  return __uint_as_float(r[0]) + __uint_as_float(r[1]);
}

#define GLL16(src, dst) \
  __builtin_amdgcn_global_load_lds((const __attribute__((address_space(1))) void*)(src), \
                                   (__attribute__((address_space(3))) void*)(dst), 16, 0, 0)

// ---------------- pre-pass: K -> bf16, row-swizzled [bh][s][384B] ----------------
__global__ __launch_bounds__(256) void prep_k(const float* __restrict__ K,
                                              unsigned short* __restrict__ Kg) {
  int idx = blockIdx.x * 256 + threadIdx.x;
  int d4 = idx % 48; int r = idx / 48;
  int h = r % H_; r /= H_;
  int s = r % S_; int b = r / S_;
  float4 f = *(const float4*)(K + (size_t)((b * S_ + s) * H_ + h) * DQ_ + d4 * 4);
  ushort4 u; u.x = f2bf(f.x); u.y = f2bf(f.y); u.z = f2bf(f.z); u.w = f2bf(f.w);
  size_t rowb = (size_t)((b * H_ + h) * S_ + s) * (DQ_ * 2);
  int cb = (d4 * 8) ^ ((s & 7) << 4);
  *(ushort4*)((char*)Kg + rowb + cb) = u;
}

// -- pre-pass: V -> bf16 V^T 16KB tiles [bh][tile64]: byte = (dv>>1)*256 +
//    (((dv&1)*128 + k*2) ^ (((dv>>1)&15)<<4)) --
__global__ __launch_bounds__(256) void prep_v(const float* __restrict__ V,
                                              unsigned short* __restrict__ Vg) {
  __shared__ float lv[64][132];
  int blk = blockIdx.x;                 // bh*32 + tile
  int tile = blk & 31, bh = blk >> 5;
  int b = bh >> 4, h = bh & 15;
  int tid = threadIdx.x;
  #pragma unroll
  for (int it = 0; it < 8; ++it) {
    int idx = it * 256 + tid;
    int s_in = idx >> 5, d4 = idx & 31;
    float4 f = *(const float4*)(V + (size_t)((b * S_ + tile * 64 + s_in) * H_ + h) * DV_ + d4 * 4);
    lv[s_in][d4 * 4 + 0] = f.x; lv[s_in][d4 * 4 + 1] = f.y;
    lv[s_in][d4 * 4 + 2] = f.z; lv[s_in][d4 * 4 + 3] = f.w;
  }
  __syncthreads();
  char* base = (char*)Vg + (size_t)blk * 16384;
  #pragma unroll
  for (int it = 0; it < 4; ++it) {
    int ch = it * 256 + tid;
    int pr = ch >> 4, ci = ch & 15;
    int orig = ci ^ (pr & 15);
    int dv = pr * 2 + (orig >> 3);
    int k0 = (orig & 7) * 8;
    short8 u;
    #pragma unroll
    for (int e = 0; e < 8; ++e) u[e] = (short)f2bf(lv[k0 + e][dv]);
    *(short8*)(base + ch * 16) = u;
  }
}

// -- main: 512 thr (4 qg x 2 kh waves), KVBLK=64, 3-buffer stage-ahead,
//    QK software-pipelined one tile ahead (overlaps softmax/PV of current tile) --
__launch_bounds__(512, 1)
__global__ void mla_fwd(const float* __restrict__ Q,
                        const unsigned short* __restrict__ Kg,
                        const unsigned short* __restrict__ Vg,
                        float* __restrict__ O) {
  __shared__ __align__(16) unsigned char SB[3][40960];   // 120KB -> 1 block/CU

  const int tid  = threadIdx.x;
  const int wid  = tid >> 6;      // 0..7
  const int lane = tid & 63;
  const int l31  = lane & 31;
  const int hi   = lane >> 5;
  const int hi16 = hi * 16;
  const int qg   = wid & 3;       // q-group (which 32 q of the 128)
  const int kh   = wid >> 2;      // k-half (which 32 k of the 64-tile)

  const int i  = blockIdx.x;      // 0..255
  const int x  = i & 7;           // XCD
  const int li = i >> 3;          // 0..31
  const int bh = x * 4 + (li >> 3);
  const int jj = li & 7;          // 0..7 -> job pair {15-jj, jj}
  const int b  = bh >> 4, h = bh & 15;

  const char* kg_bh = (const char*)Kg + (size_t)bh * S_ * (DQ_ * 2);
  const char* vg_bh = (const char*)Vg + (size_t)bh * 32 * 16384;

  const int kxor = (lane & 7) << 4;
  const int prl  = l31 >> 1;
  const int nb_  = (lane & 1) * 8 + hi;
  int voff[2];
  #pragma unroll
  for (int ks = 0; ks < 2; ++ks) {
    int n = nb_ + kh * 4 + ks * 2;
    voff[ks] = prl * 256 + ((n ^ prl) << 4);
  }

  // staging: 40 x 1KB chunks (K 0..23, V 24..39), 5 per wave
  #define STAGE(buf, t)                                                           \
    do {                                                                          \
      const char* kba = kg_bh + (size_t)(t) * 24576 + wid * 5120 + lane * 16;     \
      const char* vba = vg_bh + (size_t)(t) * 16384 - 24576 + wid * 5120 + lane * 16; \
      _Pragma("unroll")                                                           \
      for (int ci = 0; ci < 5; ++ci) {                                            \
        const int cc = wid * 5 + ci;                                              \
        const char* src = (cc < 24) ? (kba + ci * 1024) : (vba + ci * 1024);      \
        GLL16(src, &SB[buf][cc * 1024]);                                          \
      }                                                                           \
    } while (0)

  // QK^T (swapped) of one 32-k half from buffer bb, dual accumulator chains
  #define QKT(dst, bb)                                                            \
    {                                                                             \
      const char* kr_ = (const char*)&SB[bb][0] + (kh * 32 + l31) * 384;          \
      f32x16 sa_ = (f32x16)0.0f, sb_ = (f32x16)0.0f;                              \
      __builtin_amdgcn_s_setprio(1);                                              \
      _Pragma("unroll")                                                           \
      for (int d0 = 0; d0 < 12; d0 += 2) {                                        \
        const int c0 = (d0 * 32 + hi16) ^ kxor;                                   \
        const int c1 = (d0 * 32 + 32 + hi16) ^ kxor;                              \
        sa_ = __builtin_amdgcn_mfma_f32_32x32x16_bf16(*(const short8*)(kr_ + c0), qf[d0],     sa_, 0, 0, 0); \
        sb_ = __builtin_amdgcn_mfma_f32_32x32x16_bf16(*(const short8*)(kr_ + c1), qf[d0 + 1], sb_, 0, 0, 0); \
      }                                                                           \
      __builtin_amdgcn_s_setprio(0);                                              \
      dst = sa_ + sb_;                                                            \
    }

  for (int job = 0; job < 2; ++job) {
    const int qt  = job ? jj : (15 - jj);   // 128-row q tile index, 0..15
    const int wq0 = qt * 128 + qg * 32;
    const int qln = wq0 + l31;

    // ---- hoist Q B-fragments (pre-scaled) ----
    short8 qf[12];
    {
      const size_t qoff = (size_t)((b * S_ + qln) * H_ + h) * DQ_;
      #pragma unroll
      for (int d0 = 0; d0 < 12; ++d0) {
        const float* p = Q + qoff + d0 * 16 + hi * 8;
        float4 f0 = *(const float4*)(p);
        float4 f1 = *(const float4*)(p + 4);
        short8 a;
        a[0] = f2bf(f0.x * SCL2); a[1] = f2bf(f0.y * SCL2);
        a[2] = f2bf(f0.z * SCL2); a[3] = f2bf(f0.w * SCL2);
        a[4] = f2bf(f1.x * SCL2); a[5] = f2bf(f1.y * SCL2);
        a[6] = f2bf(f1.z * SCL2); a[7] = f2bf(f1.w * SCL2);
        qf[d0] = a;
      }
    }

    f32x16 o4[4];
    #pragma unroll
    for (int t2 = 0; t2 < 4; ++t2) o4[t2] = (f32x16)0.0f;
    float m = -1e30f, l = 0.0f;

    const int nt = 2 * qt + 2;

    // ---- prologue: stage tiles 0,1; QK(0) ----
    STAGE(0, 0);
    STAGE(1, 1);
    asm volatile("s_waitcnt vmcnt(5)" ::: "memory");   // tile 0 landed (own chunks)
    __builtin_amdgcn_s_barrier();                      // all waves' tile-0 chunks landed
    f32x16 sp;
    const bool act0 = (kh * 32 <= wq0 + 31);
    if (act0) QKT(sp, 0);

    for (int r = 0; r < nt; ++r) {
      const int bc = r % 3;
      const int bn = (r + 1) % 3;

      // drain own chunks (tile r+1 issued a full iter ago), align, prefetch r+2
      asm volatile("s_waitcnt vmcnt(0)" ::: "memory");
      __builtin_amdgcn_s_barrier();
      if (r + 2 < nt) STAGE((r + 2) % 3, r + 2);

      const int khb = r * 64 + kh * 32;
      const bool actR = (khb <= wq0 + 31);
      const bool nxA  = (r + 1 < nt) && (khb + 64 <= wq0 + 31);

      // ---- QK of NEXT tile (independent of this tile's softmax/PV ->
      //      MFMA pipe fills while VALU does softmax below) ----
      f32x16 sn;
      if (nxA) QKT(sn, bn);

      if (actR) {
        const char* vb = (const char*)&SB[bc][0] + 24576;
        // first half of V fragments
        short8 v00 = *(const short8*)(vb + 0 * 4096 + voff[0]);
        short8 v01 = *(const short8*)(vb + 0 * 4096 + voff[1]);
        short8 v10 = *(const short8*)(vb + 1 * 4096 + voff[0]);
        short8 v11 = *(const short8*)(vb + 1 * 4096 + voff[1]);

        // ---- mask (only near diagonal) ----
        float p_[16];
        #pragma unroll
        for (int rr = 0; rr < 16; ++rr) p_[rr] = sp[rr];
        if (khb + 31 > wq0) {
          const int rem = qln - khb - 4 * hi;
          #pragma unroll
          for (int rr = 0; rr < 16; ++rr) {
            const int kof = (rr & 3) + 8 * (rr >> 2);
            if (kof > rem) p_[rr] = -1e30f;
          }
        }

        // ---- online softmax (per-wave state; k-halves merged at job end) ----
        float t8[8];
        #pragma unroll
        for (int rr = 0; rr < 8; ++rr) t8[rr] = fmaxf(p_[rr], p_[8 + rr]);
        float t4[4];
        #pragma unroll
        for (int rr = 0; rr < 4; ++rr) t4[rr] = fmaxf(t8[rr], t8[4 + rr]);
        float mx = fmaxf(fmaxf(t4[0], t4[1]), fmaxf(t4[2], t4[3]));
        mx = pl32max(mx);
        if (__any(mx > m + 8.0f)) {        // defer-max
          float mn = fmaxf(m, mx);
          float al = hw_exp2(m - mn);
          #pragma unroll
          for (int t2 = 0; t2 < 4; ++t2) o4[t2] *= al;
          l *= al; m = mn;
        }
        #pragma unroll
        for (int rr = 0; rr < 16; ++rr) p_[rr] = hw_exp2(p_[rr] - m);
        float a8[8];
        #pragma unroll
        for (int rr = 0; rr < 8; ++rr) a8[rr] = p_[rr] + p_[8 + rr];
        float a4[4];
        #pragma unroll
        for (int rr = 0; rr < 4; ++rr) a4[rr] = a8[rr] + a8[4 + rr];
        l += (a4[0] + a4[1]) + (a4[2] + a4[3]);

        // ---- P -> B-fragments: 8 cvtpk + 4 permlane32_swap ----
        unsigned a_ = cvtpk(p_[0], p_[1]),   b2_ = cvtpk(p_[2], p_[3]);
        unsigned c_ = cvtpk(p_[4], p_[5]),   d_  = cvtpk(p_[6], p_[7]);
        unsigned e_ = cvtpk(p_[8], p_[9]),   f_  = cvtpk(p_[10], p_[11]);
        unsigned g_ = cvtpk(p_[12], p_[13]), h_  = cvtpk(p_[14], p_[15]);
        uint2v s02 = __builtin_amdgcn_permlane32_swap(a_, c_, false, false);
        uint2v s13 = __builtin_amdgcn_permlane32_swap(b2_, d_, false, false);
        uint2v s46 = __builtin_amdgcn_permlane32_swap(e_, g_, false, false);
        uint2v s57 = __builtin_amdgcn_permlane32_swap(f_, h_, false, false);
        union { unsigned u[4]; short8 s; } pb0, pb1;
        pb0.u[0] = s02[0]; pb0.u[1] = s13[0]; pb0.u[2] = s02[1]; pb0.u[3] = s13[1];
        pb1.u[0] = s46[0]; pb1.u[1] = s57[0]; pb1.u[2] = s46[1]; pb1.u[3] = s57[1];

        // second half of V fragments
        short8 v20 = *(const short8*)(vb + 2 * 4096 + voff[0]);
        short8 v21 = *(const short8*)(vb + 2 * 4096 + voff[1]);
        short8 v30 = *(const short8*)(vb + 3 * 4096 + voff[0]);
        short8 v31 = *(const short8*)(vb + 3 * 4096 + voff[1]);

        // ---- PV: 8 MFMAs ----
        __builtin_amdgcn_s_setprio(1);
        o4[0] = __builtin_amdgcn_mfma_f32_32x32x16_bf16(v00, pb0.s, o4[0], 0, 0, 0);
        o4[0] = __builtin_amdgcn_mfma_f32_32x32x16_bf16(v01, pb1.s, o4[0], 0, 0, 0);
        o4[1] = __builtin_amdgcn_mfma_f32_32x32x16_bf16(v10, pb0.s, o4[1], 0, 0, 0);
        o4[1] = __builtin_amdgcn_mfma_f32_32x32x16_bf16(v11, pb1.s, o4[1], 0, 0, 0);
        o4[2] = __builtin_amdgcn_mfma_f32_32x32x16_bf16(v20, pb0.s, o4[2], 0, 0, 0);
        o4[2] = __builtin_amdgcn_mfma_f32_32x32x16_bf16(v21, pb1.s, o4[2], 0, 0, 0);
        o4[3] = __builtin_amdgcn_mfma_f32_32x32x16_bf16(v30, pb0.s, o4[3], 0, 0, 0);
        o4[3] = __builtin_amdgcn_mfma_f32_32x32x16_bf16(v31, pb1.s, o4[3], 0, 0, 0);
        __builtin_amdgcn_s_setprio(0);
      }

      if (nxA) sp = sn;
    }

    // ---- merge the two k-half softmax states, then store ----
    float lr = pl32add(l);
    __syncthreads();                       // all compute reads of SB done
    char* mrg = (char*)&SB[0][0];          // staging dead here
    if (kh == 1) {
      float* po = (float*)(mrg + qg * 17408 + lane * 272);
      #pragma unroll
      for (int t2 = 0; t2 < 4; ++t2) {
        #pragma unroll
        for (int rr = 0; rr < 4; ++rr) {
          float4 st = { o4[t2][rr * 4 + 0], o4[t2][rr * 4 + 1],
                        o4[t2][rr * 4 + 2], o4[t2][rr * 4 + 3] };
          *(float4*)(po + t2 * 16 + rr * 4) = st;
        }
      }
      float* pm = (float*)(mrg + 69632 + (qg * 64 + lane) * 8);
      pm[0] = m; pm[1] = lr;
    }
    __syncthreads();
    if (kh == 0) {
      const float* po = (const float*)(mrg + qg * 17408 + lane * 272);
      const float* pm = (const float*)(mrg + 69632 + (qg * 64 + lane) * 8);
      const float mB = pm[0], lB = pm[1];
      const float ms = fmaxf(m, mB);
      const float wA = hw_exp2(m - ms), wB = hw_exp2(mB - ms);
      const float inv = 1.0f / (lr * wA + lB * wB);
      float* ob = O + (size_t)((b * S_ + qln) * H_ + h) * DV_;
      #pragma unroll
      for (int t2 = 0; t2 < 4; ++t2) {
        #pragma unroll
        for (int rr = 0; rr < 4; ++rr) {
          float4 vb4 = *(const float4*)(po + t2 * 16 + rr * 4);
          float4 st = { (o4[t2][rr * 4 + 0] * wA + vb4.x * wB) * inv,
                        (o4[t2][rr * 4 + 1] * wA + vb4.y * wB) * inv,
                        (o4[t2][rr * 4 + 2] * wA + vb4.z * wB) * inv,
                        (o4[t2][rr * 4 + 3] * wA + vb4.w * wB) * inv };
          *(float4*)(ob + t2 * 32 + rr * 8 + hi * 4) = st;
        }
      }
    }
    __syncthreads();                       // merge area consumed before next job
  }
  #undef STAGE
  #undef QKT
}

// ---------------- fallback (no-prep path) if ws too small ----------------
__launch_bounds__(256)
__global__ void mla_fwd_fb(const float* __restrict__ Q,
                           const float* __restrict__ K,
                           const float* __restrict__ V,
                           float* __restrict__ O) {
  __shared__ __align__(16) unsigned short Kl[2][32][200];
  __shared__ __align__(16) unsigned short Vt[2][128][40];
  __shared__ __align__(16) unsigned short Pl[4][16][40];
  const int tid = threadIdx.x, wid = tid >> 6, lane = tid & 63;
  const int l15 = lane & 15, g = lane >> 4;
  const int qtile = (int)gridDim.x - 1 - (int)blockIdx.x;
  const int bh = blockIdx.y, b = bh >> 4, h = bh & 15;
  const int q0w = qtile * 64 + wid * 16;
  const int krs = H_ * DQ_, vrs = H_ * DV_;
  short8 aq[6];
  {
    const int qoff = ((b * S_ + (q0w + l15)) * H_ + h) * DQ_;
    #pragma unroll
    for (int d0 = 0; d0 < 6; ++d0) {
      const float* p = Q + qoff + d0 * 32 + g * 8;
      float4 f0 = *(const float4*)(p); float4 f1 = *(const float4*)(p + 4);
      short8 a;
      a[0]=f2bf(f0.x); a[1]=f2bf(f0.y); a[2]=f2bf(f0.z); a[3]=f2bf(f0.w);
      a[4]=f2bf(f1.x); a[5]=f2bf(f1.y); a[6]=f2bf(f1.z); a[7]=f2bf(f1.w);
      aq[d0] = a;
    }
  }
  f32x4 o[8];
  #pragma unroll
  for (int t = 0; t < 8; ++t) o[t] = (f32x4)0.0f;
  float m[4], l[4];
  #pragma unroll
  for (int r = 0; r < 4; ++r) { m[r] = -1e30f; l[r] = 0.0f; }
  const int ntiles = qtile * 2 + 2;
  float4 kr[6], vr[4];
  {
    const float* Kb = K + ((b * S_) * H_ + h) * DQ_;
    #pragma unroll
    for (int i = 0; i < 6; ++i) { int idx = i*256+tid; int row = idx/48, c4 = idx%48;
      kr[i] = *(const float4*)(Kb + row*krs + c4*4); }
    const float* Vb = V + ((b * S_) * H_ + h) * DV_;
    #pragma unroll
    for (int i = 0; i < 4; ++i) { int idx = i*256+tid; int row = idx&31, c4 = idx>>5;
      vr[i] = *(const float4*)(Vb + row*vrs + c4*4); }
    #pragma unroll
    for (int i = 0; i < 6; ++i) { int idx = i*256+tid; int row = idx/48, c4 = idx%48;
      ushort4 u; u.x=f2bf(kr[i].x); u.y=f2bf(kr[i].y); u.z=f2bf(kr[i].z); u.w=f2bf(kr[i].w);
      *(ushort4*)&Kl[0][row][c4*4] = u; }
    #pragma unroll
    for (int i = 0; i < 4; ++i) { int idx = i*256+tid; int row = idx&31, c4 = idx>>5;
      Vt[0][c4*4+0][row]=f2bf(vr[i].x); Vt[0][c4*4+1][row]=f2bf(vr[i].y);
      Vt[0][c4*4+2][row]=f2bf(vr[i].z); Vt[0][c4*4+3][row]=f2bf(vr[i].w); }
  }
  __syncthreads();
  int cur = 0;
  for (int kt = 0; kt < ntiles; ++kt) {
    const int kbase = kt * 32;
    const bool pf = (kt + 1 < ntiles);
    if (pf) {
      const int nb = kbase + 32;
      const float* Kb = K + ((b*S_+nb)*H_ + h)*DQ_;
      #pragma unroll
      for (int i = 0; i < 6; ++i) { int idx = i*256+tid; int row = idx/48, c4 = idx%48;
        kr[i] = *(const float4*)(Kb + row*krs + c4*4); }
      const float* Vb = V + ((b*S_+nb)*H_ + h)*DV_;
      #pragma unroll
      for (int i = 0; i < 4; ++i) { int idx = i*256+tid; int row = idx&31, c4 = idx>>5;
        vr[i] = *(const float4*)(Vb + row*vrs + c4*4); }
    }
    f32x4 sa0 = (f32x4)0.0f, sa1 = (f32x4)0.0f;
    #pragma unroll
    for (int d0 = 0; d0 < 6; ++d0) {
      short8 b0 = *(const short8*)&Kl[cur][l15][d0*32 + g*8];
      sa0 = __builtin_amdgcn_mfma_f32_16x16x32_bf16(aq[d0], b0, sa0, 0, 0, 0);
      short8 b1 = *(const short8*)&Kl[cur][16+l15][d0*32 + g*8];
      sa1 = __builtin_amdgcn_mfma_f32_16x16x32_bf16(aq[d0], b1, sa1, 0, 0, 0);
    }
    float p0[4], p1[4];
    #pragma unroll
    for (int r = 0; r < 4; ++r) {
      const int qg = q0w + 4*g + r;
      float s0 = sa0[r]*SCL2, s1 = sa1[r]*SCL2;
      if (kbase + l15 > qg) s0 = -1e30f;
      if (kbase + 16 + l15 > qg) s1 = -1e30f;
      p0[r] = s0; p1[r] = s1;
    }
    #pragma unroll
    for (int r = 0; r < 4; ++r) {
      float rm = fmaxf(p0[r], p1[r]);
      #pragma unroll
      for (int off = 1; off < 16; off <<= 1) rm = fmaxf(rm, __shfl_xor(rm, off));
      float mn = fmaxf(m[r], rm);
      float alpha = exp2f(m[r] - mn); m[r] = mn;
      float e0 = exp2f(p0[r] - mn), e1 = exp2f(p1[r] - mn);
      p0[r] = e0; p1[r] = e1;
      float rsum = e0 + e1;
      #pragma unroll
      for (int off = 1; off < 16; off <<= 1) rsum += __shfl_xor(rsum, off);
      l[r] = l[r]*alpha + rsum;
      #pragma unroll
      for (int t = 0; t < 8; ++t) o[t][r] *= alpha;
    }
    #pragma unroll
    for (int r = 0; r < 4; ++r) {
      Pl[wid][4*g+r][l15]      = f2bf(p0[r]);
      Pl[wid][4*g+r][16+l15]   = f2bf(p1[r]);
    }
    short8 pa = *(const short8*)&Pl[wid][l15][g*8];
    #pragma unroll
    for (int t = 0; t < 8; ++t) {
      short8 vb = *(const short8*)&Vt[cur][t*16+l15][g*8];
      o[t] = __builtin_amdgcn_mfma_f32_16x16x32_bf16(pa, vb, o[t], 0, 0, 0);
    }
    if (pf) {
      #pragma unroll
      for (int i = 0; i < 6; ++i) { int idx = i*256+tid; int row = idx/48, c4 = idx%48;
        ushort4 u; u.x=f2bf(kr[i].x); u.y=f2bf(kr[i].y); u.z=f2bf(kr[i].z); u.w=f2bf(kr[i].w);
        *(ushort4*)&Kl[cur^1][row][c4*4] = u; }
      #pragma unroll
      for (int i = 0; i < 4; ++i) { int idx = i*256+tid; int row = idx&31, c4 = idx>>5;
        Vt[cur^1][c4*4+0][row]=f2bf(vr[i].x); Vt[cur^1][c4*4+1][row]=f2bf(vr[i].y);
        Vt[cur^1][c4*4+2][row]=f2bf(vr[i].z); Vt[cur^1][c4*4+3][row]=f2bf(vr[i].w); }
    }
    __syncthreads();
    cur ^= 1;
  }
  #pragma unroll
  for (int r = 0; r < 4; ++r) {
    const int qg = q0w + 4*g + r;
    const float inv = 1.0f / l[r];
    #pragma unroll
    for (int t = 0; t < 8; ++t)
      O[((b*S_+qg)*H_ + h)*DV_ + t*16 + l15] = o[t][r] * inv;
  }
}

extern "C" void kernel_launch(void* const* d_in, const int* in_sizes, int n_in,
                              void* d_out, int out_size, void* d_ws, size_t ws_size,
                              hipStream_t stream) {
  const float* q = (const float*)d_in[0];
  const float* k = (const float*)d_in[1];
  const float* v = (const float*)d_in[2];
  float* out = (float*)d_out;

  if (ws_size >= KG_BYTES + VG_BYTES) {
    unsigned short* Kg = (unsigned short*)d_ws;
    unsigned short* Vg = (unsigned short*)((char*)d_ws + KG_BYTES);
    prep_k<<<dim3((B_ * S_ * H_ * 48) / 256), dim3(256), 0, stream>>>(k, Kg);
    prep_v<<<dim3(B_ * H_ * 32), dim3(256), 0, stream>>>(v, Vg);
    mla_fwd<<<dim3(256), dim3(512), 0, stream>>>(q, Kg, Vg, out);
  } else {
    dim3 grid(S_ / 64, B_ * H_);
    mla_fwd_fb<<<grid, dim3(256), 0, stream>>>(q, k, v, out);
  }
}

// Round 13
// 91.377 us; speedup vs baseline: 1.0549x; 1.0549x over previous
//
#include <hip/hip_runtime.h>

#define B_ 2
#define S_ 2048
#define H_ 16
#define DQ_ 192
#define DV_ 128
// log2(e)/sqrt(192): folded into Q at hoist time
#define SCL2 0.10411163731422901f

typedef short short8 __attribute__((ext_vector_type(8)));
typedef float f32x4 __attribute__((ext_vector_type(4)));
typedef float f32x16 __attribute__((ext_vector_type(16)));
typedef unsigned uint2v __attribute__((ext_vector_type(2)));

#define KG_BYTES ((size_t)25165824)   // B*H*S*DQ*2
#define VG_BYTES ((size_t)16777216)   // B*H*DV*S*2

__device__ __forceinline__ unsigned short f2bf(float f) {
  union { float f; unsigned u; } x; x.f = f;
  unsigned r = x.u + 0x7FFFu + ((x.u >> 16) & 1u);   // RNE
  return (unsigned short)(r >> 16);
}

__device__ __forceinline__ float hw_exp2(float x) {
  float r; asm("v_exp_f32 %0, %1" : "=v"(r) : "v"(x)); return r;
}
__device__ __forceinline__ unsigned cvtpk(float lo, float hi) {
  unsigned r; asm("v_cvt_pk_bf16_f32 %0, %1, %2" : "=v"(r) : "v"(lo), "v"(hi)); return r;
}
__device__ __forceinline__ float pl32max(float x) {
  uint2v r = __builtin_amdgcn_permlane32_swap(__float_as_uint(x), __float_as_uint(x), false, false);
  return fmaxf(__uint_as_float(r[0]), __uint_as_float(r[1]));
}
__device__ __forceinline__ float pl32add(float x) {
  uint2v r = __builtin_amdgcn_permlane32_swap(__float_as_uint(x), __float_as_uint(x), false, false);
  return __uint_as_float(r[0]) + __uint_as_float(r[1]);
}

#define GLL16(src, dst) \
  __builtin_amdgcn_global_load_lds((const __attribute__((address_space(1))) void*)(src), \
                                   (__attribute__((address_space(3))) void*)(dst), 16, 0, 0)

// ---------------- pre-pass: K -> bf16, row-swizzled [bh][s][384B] ----------------
__global__ __launch_bounds__(256) void prep_k(const float* __restrict__ K,
                                              unsigned short* __restrict__ Kg) {
  int idx = blockIdx.x * 256 + threadIdx.x;
  int d4 = idx % 48; int r = idx / 48;
  int h = r % H_; r /= H_;
  int s = r % S_; int b = r / S_;
  float4 f = *(const float4*)(K + (size_t)((b * S_ + s) * H_ + h) * DQ_ + d4 * 4);
  ushort4 u; u.x = f2bf(f.x); u.y = f2bf(f.y); u.z = f2bf(f.z); u.w = f2bf(f.w);
  size_t rowb = (size_t)((b * H_ + h) * S_ + s) * (DQ_ * 2);
  int cb = (d4 * 8) ^ ((s & 7) << 4);
  *(ushort4*)((char*)Kg + rowb + cb) = u;
}

// -- pre-pass: V -> bf16 V^T 16KB tiles [bh][tile64]: byte = (dv>>1)*256 +
//    (((dv&1)*128 + k*2) ^ (((dv>>1)&15)<<4)) --
__global__ __launch_bounds__(256) void prep_v(const float* __restrict__ V,
                                              unsigned short* __restrict__ Vg) {
  __shared__ float lv[64][132];
  int blk = blockIdx.x;                 // bh*32 + tile
  int tile = blk & 31, bh = blk >> 5;
  int b = bh >> 4, h = bh & 15;
  int tid = threadIdx.x;
  #pragma unroll
  for (int it = 0; it < 8; ++it) {
    int idx = it * 256 + tid;
    int s_in = idx >> 5, d4 = idx & 31;
    float4 f = *(const float4*)(V + (size_t)((b * S_ + tile * 64 + s_in) * H_ + h) * DV_ + d4 * 4);
    lv[s_in][d4 * 4 + 0] = f.x; lv[s_in][d4 * 4 + 1] = f.y;
    lv[s_in][d4 * 4 + 2] = f.z; lv[s_in][d4 * 4 + 3] = f.w;
  }
  __syncthreads();
  char* base = (char*)Vg + (size_t)blk * 16384;
  #pragma unroll
  for (int it = 0; it < 4; ++it) {
    int ch = it * 256 + tid;
    int pr = ch >> 4, ci = ch & 15;
    int orig = ci ^ (pr & 15);
    int dv = pr * 2 + (orig >> 3);
    int k0 = (orig & 7) * 8;
    short8 u;
    #pragma unroll
    for (int e = 0; e < 8; ++e) u[e] = (short)f2bf(lv[k0 + e][dv]);
    *(short8*)(base + ch * 16) = u;
  }
}

// -- main: 512 thr (4 qg x 2 kh waves), 128q/block, KVBLK=64, depth-2 counted-vmcnt
//    pipeline over 3 LDS buffers; jobs {15-j, j} -> uniform 34 iters; 256 blocks.
//    Race-fixed: per-iter wait is vmcnt(5) (tile kt landed, kt+1 in flight). --
__launch_bounds__(512, 1)
__global__ void mla_fwd(const float* __restrict__ Q,
                        const unsigned short* __restrict__ Kg,
                        const unsigned short* __restrict__ Vg,
                        float* __restrict__ O) {
  // 3 x [ K 24KB (64 x 384B) | V 16KB ] = 120KB -> exactly 1 block/CU
  __shared__ __align__(16) unsigned char SB[3][40960];

  const int tid  = threadIdx.x;
  const int wid  = tid >> 6;      // 0..7
  const int lane = tid & 63;
  const int l31  = lane & 31;
  const int hi   = lane >> 5;
  const int hi16 = hi * 16;
  const int qg   = wid & 3;       // q-group (which 32 q of the 128)
  const int kh   = wid >> 2;      // k-half (which 32 k of the 64-tile)

  const int i  = blockIdx.x;      // 0..255
  const int x  = i & 7;           // XCD
  const int li = i >> 3;          // 0..31
  const int bh = x * 4 + (li >> 3);
  const int jj = li & 7;          // 0..7 -> job pair {15-jj, jj}
  const int b  = bh >> 4, h = bh & 15;

  const char* kg_bh = (const char*)Kg + (size_t)bh * S_ * (DQ_ * 2);
  const char* vg_bh = (const char*)Vg + (size_t)bh * 32 * 16384;

  // lane-constant addressing
  const int kxor = (lane & 7) << 4;
  const int prl  = l31 >> 1;
  const int nb_  = (lane & 1) * 8 + hi;
  int voff[2];
  #pragma unroll
  for (int ks = 0; ks < 2; ++ks) {
    int n = nb_ + kh * 4 + ks * 2;
    voff[ks] = prl * 256 + ((n ^ prl) << 4);
  }

  // staging: 40 x 1KB chunks (K 0..23, V 24..39), 5 per wave
  #define STAGE(buf, t)                                                           \
    do {                                                                          \
      const char* kba = kg_bh + (size_t)(t) * 24576 + wid * 5120 + lane * 16;     \
      const char* vba = vg_bh + (size_t)(t) * 16384 - 24576 + wid * 5120 + lane * 16; \
      _Pragma("unroll")                                                           \
      for (int ci = 0; ci < 5; ++ci) {                                            \
        const int cc = wid * 5 + ci;                                              \
        const char* src = (cc < 24) ? (kba + ci * 1024) : (vba + ci * 1024);      \
        GLL16(src, &SB[buf][cc * 1024]);                                          \
      }                                                                           \
    } while (0)

  for (int job = 0; job < 2; ++job) {
    const int qt  = job ? jj : (15 - jj);   // 128-row q tile index, 0..15
    const int wq0 = qt * 128 + qg * 32;
    const int qln = wq0 + l31;

    // ---- hoist Q B-fragments (pre-scaled) ----
    short8 qf[12];
    {
      const size_t qoff = (size_t)((b * S_ + qln) * H_ + h) * DQ_;
      #pragma unroll
      for (int d0 = 0; d0 < 12; ++d0) {
        const float* p = Q + qoff + d0 * 16 + hi * 8;
        float4 f0 = *(const float4*)(p);
        float4 f1 = *(const float4*)(p + 4);
        short8 a;
        a[0] = f2bf(f0.x * SCL2); a[1] = f2bf(f0.y * SCL2);
        a[2] = f2bf(f0.z * SCL2); a[3] = f2bf(f0.w * SCL2);
        a[4] = f2bf(f1.x * SCL2); a[5] = f2bf(f1.y * SCL2);
        a[6] = f2bf(f1.z * SCL2); a[7] = f2bf(f1.w * SCL2);
        qf[d0] = a;
      }
    }

    f32x16 o4[4];
    #pragma unroll
    for (int t2 = 0; t2 < 4; ++t2) o4[t2] = (f32x16)0.0f;
    float m = -1e30f, l = 0.0f;

    const int ntiles = 2 * qt + 2;

    // ---- prologue: stage tiles 0 and 1 ----
    STAGE(0, 0);
    if (ntiles > 1) STAGE(1, 1);

    int bc = 0;                            // compute buffer = kt % 3
    for (int kt = 0; kt < ntiles; ++kt) {
      // wait for tile kt (counted: only tile kt+1's 5 chunks may stay in flight)
      if (kt + 1 < ntiles) asm volatile("s_waitcnt vmcnt(5)" ::: "memory");
      else                 asm volatile("s_waitcnt vmcnt(0)" ::: "memory");
      __builtin_amdgcn_s_barrier();
      // stage tile kt+2 into the buffer freed at the barrier ((kt-1)%3)
      if (kt + 2 < ntiles) {
        int bs = bc - 1; if (bs < 0) bs = 2;
        STAGE(bs, kt + 2);
      }

      const int kbase = kt * 64;
      const int khb = kbase + kh * 32;     // this wave's k base

      if (khb <= wq0 + 31) {               // wave-uniform active check
        // ---- QK^T swapped on this wave's 32-k half: 12 MFMAs ----
        const char* kr = (const char*)&SB[bc][0] + (kh * 32 + l31) * 384;
        f32x16 s = (f32x16)0.0f;
        __builtin_amdgcn_s_setprio(1);
        #pragma unroll
        for (int d0 = 0; d0 < 12; ++d0) {
          const int col = (d0 * 32 + hi16) ^ kxor;
          s = __builtin_amdgcn_mfma_f32_32x32x16_bf16(*(const short8*)(kr + col), qf[d0], s, 0, 0, 0);
        }
        __builtin_amdgcn_s_setprio(0);

        // ---- V fragments (latency hides under softmax) ----
        const char* vb = (const char*)&SB[bc][0] + 24576;
        short8 v00 = *(const short8*)(vb + 0 * 4096 + voff[0]);
        short8 v01 = *(const short8*)(vb + 0 * 4096 + voff[1]);
        short8 v10 = *(const short8*)(vb + 1 * 4096 + voff[0]);
        short8 v11 = *(const short8*)(vb + 1 * 4096 + voff[1]);
        short8 v20 = *(const short8*)(vb + 2 * 4096 + voff[0]);
        short8 v21 = *(const short8*)(vb + 2 * 4096 + voff[1]);
        short8 v30 = *(const short8*)(vb + 3 * 4096 + voff[0]);
        short8 v31 = *(const short8*)(vb + 3 * 4096 + voff[1]);

        // ---- mask (only near diagonal) ----
        float p_[16];
        #pragma unroll
        for (int r = 0; r < 16; ++r) p_[r] = s[r];
        if (khb + 31 > wq0) {
          const int rem = qln - khb - 4 * hi;
          #pragma unroll
          for (int r = 0; r < 16; ++r) {
            const int kof = (r & 3) + 8 * (r >> 2);
            if (kof > rem) p_[r] = -1e30f;
          }
        }

        // ---- online softmax (per-wave state; k-halves merged at job end) ----
        float t8[8];
        #pragma unroll
        for (int r = 0; r < 8; ++r) t8[r] = fmaxf(p_[r], p_[8 + r]);
        float t4[4];
        #pragma unroll
        for (int r = 0; r < 4; ++r) t4[r] = fmaxf(t8[r], t8[4 + r]);
        float mx = fmaxf(fmaxf(t4[0], t4[1]), fmaxf(t4[2], t4[3]));
        mx = pl32max(mx);
        if (__any(mx > m + 8.0f)) {        // defer-max
          float mn = fmaxf(m, mx);
          float al = hw_exp2(m - mn);
          #pragma unroll
          for (int t2 = 0; t2 < 4; ++t2) o4[t2] *= al;
          l *= al; m = mn;
        }
        #pragma unroll
        for (int rr = 0; rr < 16; ++rr) p_[rr] = hw_exp2(p_[rr] - m);
        float a8[8];
        #pragma unroll
        for (int r = 0; r < 8; ++r) a8[r] = p_[r] + p_[8 + r];
        float a4[4];
        #pragma unroll
        for (int r = 0; r < 4; ++r) a4[r] = a8[r] + a8[4 + r];
        l += (a4[0] + a4[1]) + (a4[2] + a4[3]);

        // ---- P -> B-fragments: 8 cvtpk + 4 permlane32_swap ----
        unsigned a_ = cvtpk(p_[0], p_[1]),   b2_ = cvtpk(p_[2], p_[3]);
        unsigned c_ = cvtpk(p_[4], p_[5]),   d_  = cvtpk(p_[6], p_[7]);
        unsigned e_ = cvtpk(p_[8], p_[9]),   f_  = cvtpk(p_[10], p_[11]);
        unsigned g_ = cvtpk(p_[12], p_[13]), h_  = cvtpk(p_[14], p_[15]);
        uint2v s02 = __builtin_amdgcn_permlane32_swap(a_, c_, false, false);
        uint2v s13 = __builtin_amdgcn_permlane32_swap(b2_, d_, false, false);
        uint2v s46 = __builtin_amdgcn_permlane32_swap(e_, g_, false, false);
        uint2v s57 = __builtin_amdgcn_permlane32_swap(f_, h_, false, false);
        union { unsigned u[4]; short8 s; } pb0, pb1;
        pb0.u[0] = s02[0]; pb0.u[1] = s13[0]; pb0.u[2] = s02[1]; pb0.u[3] = s13[1];
        pb1.u[0] = s46[0]; pb1.u[1] = s57[0]; pb1.u[2] = s46[1]; pb1.u[3] = s57[1];

        // ---- PV: 8 MFMAs ----
        __builtin_amdgcn_s_setprio(1);
        o4[0] = __builtin_amdgcn_mfma_f32_32x32x16_bf16(v00, pb0.s, o4[0], 0, 0, 0);
        o4[0] = __builtin_amdgcn_mfma_f32_32x32x16_bf16(v01, pb1.s, o4[0], 0, 0, 0);
        o4[1] = __builtin_amdgcn_mfma_f32_32x32x16_bf16(v10, pb0.s, o4[1], 0, 0, 0);
        o4[1] = __builtin_amdgcn_mfma_f32_32x32x16_bf16(v11, pb1.s, o4[1], 0, 0, 0);
        o4[2] = __builtin_amdgcn_mfma_f32_32x32x16_bf16(v20, pb0.s, o4[2], 0, 0, 0);
        o4[2] = __builtin_amdgcn_mfma_f32_32x32x16_bf16(v21, pb1.s, o4[2], 0, 0, 0);
        o4[3] = __builtin_amdgcn_mfma_f32_32x32x16_bf16(v30, pb0.s, o4[3], 0, 0, 0);
        o4[3] = __builtin_amdgcn_mfma_f32_32x32x16_bf16(v31, pb1.s, o4[3], 0, 0, 0);
        __builtin_amdgcn_s_setprio(0);
      }

      ++bc; if (bc == 3) bc = 0;
    }

    // ---- merge the two k-half softmax states, then store ----
    float lr = pl32add(l);
    __syncthreads();                       // all compute reads of SB done
    char* mrg = (char*)&SB[0][0];          // staging dead (vmcnt 0 at last iter)
    if (kh == 1) {
      float* po = (float*)(mrg + qg * 17408 + lane * 272);
      #pragma unroll
      for (int t2 = 0; t2 < 4; ++t2) {
        #pragma unroll
        for (int rr = 0; rr < 4; ++rr) {
          float4 st = { o4[t2][rr * 4 + 0], o4[t2][rr * 4 + 1],
                        o4[t2][rr * 4 + 2], o4[t2][rr * 4 + 3] };
          *(float4*)(po + t2 * 16 + rr * 4) = st;
        }
      }
      float* pm = (float*)(mrg + 69632 + (qg * 64 + lane) * 8);
      pm[0] = m; pm[1] = lr;
    }
    __syncthreads();
    if (kh == 0) {
      const float* po = (const float*)(mrg + qg * 17408 + lane * 272);
      const float* pm = (const float*)(mrg + 69632 + (qg * 64 + lane) * 8);
      const float mB = pm[0], lB = pm[1];
      const float ms = fmaxf(m, mB);
      const float wA = hw_exp2(m - ms), wB = hw_exp2(mB - ms);
      const float inv = 1.0f / (lr * wA + lB * wB);
      float* ob = O + (size_t)((b * S_ + qln) * H_ + h) * DV_;
      #pragma unroll
      for (int t2 = 0; t2 < 4; ++t2) {
        #pragma unroll
        for (int rr = 0; rr < 4; ++rr) {
          float4 vb4 = *(const float4*)(po + t2 * 16 + rr * 4);
          float4 st = { (o4[t2][rr * 4 + 0] * wA + vb4.x * wB) * inv,
                        (o4[t2][rr * 4 + 1] * wA + vb4.y * wB) * inv,
                        (o4[t2][rr * 4 + 2] * wA + vb4.z * wB) * inv,
                        (o4[t2][rr * 4 + 3] * wA + vb4.w * wB) * inv };
          *(float4*)(ob + t2 * 32 + rr * 8 + hi * 4) = st;
        }
      }
    }
    __syncthreads();                       // merge area consumed before next job
  }
  #undef STAGE
}

// ---------------- fallback (no-prep path) if ws too small ----------------
__launch_bounds__(256)
__global__ void mla_fwd_fb(const float* __restrict__ Q,
                           const float* __restrict__ K,
                           const float* __restrict__ V,
                           float* __restrict__ O) {
  __shared__ __align__(16) unsigned short Kl[2][32][200];
  __shared__ __align__(16) unsigned short Vt[2][128][40];
  __shared__ __align__(16) unsigned short Pl[4][16][40];
  const int tid = threadIdx.x, wid = tid >> 6, lane = tid & 63;
  const int l15 = lane & 15, g = lane >> 4;
  const int qtile = (int)gridDim.x - 1 - (int)blockIdx.x;
  const int bh = blockIdx.y, b = bh >> 4, h = bh & 15;
  const int q0w = qtile * 64 + wid * 16;
  const int krs = H_ * DQ_, vrs = H_ * DV_;
  short8 aq[6];
  {
    const int qoff = ((b * S_ + (q0w + l15)) * H_ + h) * DQ_;
    #pragma unroll
    for (int d0 = 0; d0 < 6; ++d0) {
      const float* p = Q + qoff + d0 * 32 + g * 8;
      float4 f0 = *(const float4*)(p); float4 f1 = *(const float4*)(p + 4);
      short8 a;
      a[0]=f2bf(f0.x); a[1]=f2bf(f0.y); a[2]=f2bf(f0.z); a[3]=f2bf(f0.w);
      a[4]=f2bf(f1.x); a[5]=f2bf(f1.y); a[6]=f2bf(f1.z); a[7]=f2bf(f1.w);
      aq[d0] = a;
    }
  }
  f32x4 o[8];
  #pragma unroll
  for (int t = 0; t < 8; ++t) o[t] = (f32x4)0.0f;
  float m[4], l[4];
  #pragma unroll
  for (int r = 0; r < 4; ++r) { m[r] = -1e30f; l[r] = 0.0f; }
  const int ntiles = qtile * 2 + 2;
  float4 kr[6], vr[4];
  {
    const float* Kb = K + ((b * S_) * H_ + h) * DQ_;
    #pragma unroll
    for (int i = 0; i < 6; ++i) { int idx = i*256+tid; int row = idx/48, c4 = idx%48;
      kr[i] = *(const float4*)(Kb + row*krs + c4*4); }
    const float* Vb = V + ((b * S_) * H_ + h) * DV_;
    #pragma unroll
    for (int i = 0; i < 4; ++i) { int idx = i*256+tid; int row = idx&31, c4 = idx>>5;
      vr[i] = *(const float4*)(Vb + row*vrs + c4*4); }
    #pragma unroll
    for (int i = 0; i < 6; ++i) { int idx = i*256+tid; int row = idx/48, c4 = idx%48;
      ushort4 u; u.x=f2bf(kr[i].x); u.y=f2bf(kr[i].y); u.z=f2bf(kr[i].z); u.w=f2bf(kr[i].w);
      *(ushort4*)&Kl[0][row][c4*4] = u; }
    #pragma unroll
    for (int i = 0; i < 4; ++i) { int idx = i*256+tid; int row = idx&31, c4 = idx>>5;
      Vt[0][c4*4+0][row]=f2bf(vr[i].x); Vt[0][c4*4+1][row]=f2bf(vr[i].y);
      Vt[0][c4*4+2][row]=f2bf(vr[i].z); Vt[0][c4*4+3][row]=f2bf(vr[i].w); }
  }
  __syncthreads();
  int cur = 0;
  for (int kt = 0; kt < ntiles; ++kt) {
    const int kbase = kt * 32;
    const bool pf = (kt + 1 < ntiles);
    if (pf) {
      const int nb = kbase + 32;
      const float* Kb = K + ((b*S_+nb)*H_ + h)*DQ_;
      #pragma unroll
      for (int i = 0; i < 6; ++i) { int idx = i*256+tid; int row = idx/48, c4 = idx%48;
        kr[i] = *(const float4*)(Kb + row*krs + c4*4); }
      const float* Vb = V + ((b*S_+nb)*H_ + h)*DV_;
      #pragma unroll
      for (int i = 0; i < 4; ++i) { int idx = i*256+tid; int row = idx&31, c4 = idx>>5;
        vr[i] = *(const float4*)(Vb + row*vrs + c4*4); }
    }
    f32x4 sa0 = (f32x4)0.0f, sa1 = (f32x4)0.0f;
    #pragma unroll
    for (int d0 = 0; d0 < 6; ++d0) {
      short8 b0 = *(const short8*)&Kl[cur][l15][d0*32 + g*8];
      sa0 = __builtin_amdgcn_mfma_f32_16x16x32_bf16(aq[d0], b0, sa0, 0, 0, 0);
      short8 b1 = *(const short8*)&Kl[cur][16+l15][d0*32 + g*8];
      sa1 = __builtin_amdgcn_mfma_f32_16x16x32_bf16(aq[d0], b1, sa1, 0, 0, 0);
    }
    float p0[4], p1[4];
    #pragma unroll
    for (int r = 0; r < 4; ++r) {
      const int qg = q0w + 4*g + r;
      float s0 = sa0[r]*SCL2, s1 = sa1[r]*SCL2;
      if (kbase + l15 > qg) s0 = -1e30f;
      if (kbase + 16 + l15 > qg) s1 = -1e30f;
      p0[r] = s0; p1[r] = s1;
    }
    #pragma unroll
    for (int r = 0; r < 4; ++r) {
      float rm = fmaxf(p0[r], p1[r]);
      #pragma unroll
      for (int off = 1; off < 16; off <<= 1) rm = fmaxf(rm, __shfl_xor(rm, off));
      float mn = fmaxf(m[r], rm);
      float alpha = exp2f(m[r] - mn); m[r] = mn;
      float e0 = exp2f(p0[r] - mn), e1 = exp2f(p1[r] - mn);
      p0[r] = e0; p1[r] = e1;
      float rsum = e0 + e1;
      #pragma unroll
      for (int off = 1; off < 16; off <<= 1) rsum += __shfl_xor(rsum, off);
      l[r] = l[r]*alpha + rsum;
      #pragma unroll
      for (int t = 0; t < 8; ++t) o[t][r] *= alpha;
    }
    #pragma unroll
    for (int r = 0; r < 4; ++r) {
      Pl[wid][4*g+r][l15]      = f2bf(p0[r]);
      Pl[wid][4*g+r][16+l15]   = f2bf(p1[r]);
    }
    short8 pa = *(const short8*)&Pl[wid][l15][g*8];
    #pragma unroll
    for (int t = 0; t < 8; ++t) {
      short8 vb = *(const short8*)&Vt[cur][t*16+l15][g*8];
      o[t] = __builtin_amdgcn_mfma_f32_16x16x32_bf16(pa, vb, o[t], 0, 0, 0);
    }
    if (pf) {
      #pragma unroll
      for (int i = 0; i < 6; ++i) { int idx = i*256+tid; int row = idx/48, c4 = idx%48;
        ushort4 u; u.x=f2bf(kr[i].x); u.y=f2bf(kr[i].y); u.z=f2bf(kr[i].z); u.w=f2bf(kr[i].w);
        *(ushort4*)&Kl[cur^1][row][c4*4] = u; }
      #pragma unroll
      for (int i = 0; i < 4; ++i) { int idx = i*256+tid; int row = idx&31, c4 = idx>>5;
        Vt[cur^1][c4*4+0][row]=f2bf(vr[i].x); Vt[cur^1][c4*4+1][row]=f2bf(vr[i].y);
        Vt[cur^1][c4*4+2][row]=f2bf(vr[i].z); Vt[cur^1][c4*4+3][row]=f2bf(vr[i].w); }
    }
    __syncthreads();
    cur ^= 1;
  }
  #pragma unroll
  for (int r = 0; r < 4; ++r) {
    const int qg = q0w + 4*g + r;
    const float inv = 1.0f / l[r];
    #pragma unroll
    for (int t = 0; t < 8; ++t)
      O[((b*S_+qg)*H_ + h)*DV_ + t*16 + l15] = o[t][r] * inv;
  }
}

extern "C" void kernel_launch(void* const* d_in, const int* in_sizes, int n_in,
                              void* d_out, int out_size, void* d_ws, size_t ws_size,
                              hipStream_t stream) {
  const float* q = (const float*)d_in[0];
  const float* k = (const float*)d_in[1];
  const float* v = (const float*)d_in[2];
  float* out = (float*)d_out;

  if (ws_size >= KG_BYTES + VG_BYTES) {
    unsigned short* Kg = (unsigned short*)d_ws;
    unsigned short* Vg = (unsigned short*)((char*)d_ws + KG_BYTES);
    prep_k<<<dim3((B_ * S_ * H_ * 48) / 256), dim3(256), 0, stream>>>(k, Kg);
    prep_v<<<dim3(B_ * H_ * 32), dim3(256), 0, stream>>>(v, Vg);
    mla_fwd<<<dim3(256), dim3(512), 0, stream>>>(q, Kg, Vg, out);
  } else {
    dim3 grid(S_ / 64, B_ * H_);
    mla_fwd_fb<<<grid, dim3(256), 0, stream>>>(q, k, v, out);
  }
}

// Round 14
// 90.492 us; speedup vs baseline: 1.0653x; 1.0098x over previous
//
#include <hip/hip_runtime.h>

#define B_ 2
#define S_ 2048
#define H_ 16
#define DQ_ 192
#define DV_ 128
// log2(e)/sqrt(192): folded into Q at hoist time
#define SCL2 0.10411163731422901f

typedef short short8 __attribute__((ext_vector_type(8)));
typedef float f32x4 __attribute__((ext_vector_type(4)));
typedef float f32x16 __attribute__((ext_vector_type(16)));
typedef unsigned uint2v __attribute__((ext_vector_type(2)));

#define KG_BYTES ((size_t)25165824)   // B*H*S*DQ*2
#define VG_BYTES ((size_t)16777216)   // B*H*DV*S*2

__device__ __forceinline__ unsigned short f2bf(float f) {
  union { float f; unsigned u; } x; x.f = f;
  unsigned r = x.u + 0x7FFFu + ((x.u >> 16) & 1u);   // RNE
  return (unsigned short)(r >> 16);
}

__device__ __forceinline__ float hw_exp2(float x) {
  float r; asm("v_exp_f32 %0, %1" : "=v"(r) : "v"(x)); return r;
}
__device__ __forceinline__ unsigned cvtpk(float lo, float hi) {
  unsigned r; asm("v_cvt_pk_bf16_f32 %0, %1, %2" : "=v"(r) : "v"(lo), "v"(hi)); return r;
}
__device__ __forceinline__ float max3f(float a, float b, float c) {
  float r; asm("v_max3_f32 %0, %1, %2, %3" : "=v"(r) : "v"(a), "v"(b), "v"(c)); return r;
}
__device__ __forceinline__ float pl32max(float x) {
  uint2v r = __builtin_amdgcn_permlane32_swap(__float_as_uint(x), __float_as_uint(x), false, false);
  return fmaxf(__uint_as_float(r[0]), __uint_as_float(r[1]));
}
__device__ __forceinline__ float pl32add(float x) {
  uint2v r = __builtin_amdgcn_permlane32_swap(__float_as_uint(x), __float_as_uint(x), false, false);
  return __uint_as_float(r[0]) + __uint_as_float(r[1]);
}

#define GLL16(src, dst) \
  __builtin_amdgcn_global_load_lds((const __attribute__((address_space(1))) void*)(src), \
                                   (__attribute__((address_space(3))) void*)(dst), 16, 0, 0)

// ---- merged pre-pass: K -> bf16 swizzled rows; V -> bf16 V^T swizzled tiles ----
// blocks [0, 12288): K.  blocks [12288, 13312): V.
__global__ __launch_bounds__(256) void prep_kv(const float* __restrict__ K,
                                               const float* __restrict__ V,
                                               unsigned short* __restrict__ Kg,
                                               unsigned short* __restrict__ Vg) {
  __shared__ float lv[64][132];
  const int bid = blockIdx.x;
  const int tid = threadIdx.x;
  if (bid < 12288) {
    // K -> bf16, row-swizzled [bh][s][384B]
    int idx = bid * 256 + tid;
    int d4 = idx % 48; int r = idx / 48;
    int h = r % H_; r /= H_;
    int s = r % S_; int b = r / S_;
    float4 f = *(const float4*)(K + (size_t)((b * S_ + s) * H_ + h) * DQ_ + d4 * 4);
    ushort4 u; u.x = f2bf(f.x); u.y = f2bf(f.y); u.z = f2bf(f.z); u.w = f2bf(f.w);
    size_t rowb = (size_t)((b * H_ + h) * S_ + s) * (DQ_ * 2);
    int cb = (d4 * 8) ^ ((s & 7) << 4);
    *(ushort4*)((char*)Kg + rowb + cb) = u;
  } else {
    // V -> bf16 V^T 16KB tiles [bh][tile64]: byte = (dv>>1)*256 +
    //   (((dv&1)*128 + k*2) ^ (((dv>>1)&15)<<4))
    int blk = bid - 12288;              // bh*32 + tile
    int tile = blk & 31, bh = blk >> 5;
    int b = bh >> 4, h = bh & 15;
    #pragma unroll
    for (int it = 0; it < 8; ++it) {
      int idx = it * 256 + tid;
      int s_in = idx >> 5, d4 = idx & 31;
      float4 f = *(const float4*)(V + (size_t)((b * S_ + tile * 64 + s_in) * H_ + h) * DV_ + d4 * 4);
      lv[s_in][d4 * 4 + 0] = f.x; lv[s_in][d4 * 4 + 1] = f.y;
      lv[s_in][d4 * 4 + 2] = f.z; lv[s_in][d4 * 4 + 3] = f.w;
    }
    __syncthreads();
    char* base = (char*)Vg + (size_t)blk * 16384;
    #pragma unroll
    for (int it = 0; it < 4; ++it) {
      int ch = it * 256 + tid;
      int pr = ch >> 4, ci = ch & 15;
      int orig = ci ^ (pr & 15);
      int dv = pr * 2 + (orig >> 3);
      int k0 = (orig & 7) * 8;
      short8 u;
      #pragma unroll
      for (int e = 0; e < 8; ++e) u[e] = (short)f2bf(lv[k0 + e][dv]);
      *(short8*)(base + ch * 16) = u;
    }
  }
}

// -- main: 512 thr (4 qg x 2 kh waves), 128q/block, KVBLK=64, depth-2 counted-vmcnt
//    pipeline over 3 LDS buffers; jobs {15-j, j} -> uniform 34 iters; 256 blocks. --
__launch_bounds__(512, 1)
__global__ void mla_fwd(const float* __restrict__ Q,
                        const unsigned short* __restrict__ Kg,
                        const unsigned short* __restrict__ Vg,
                        float* __restrict__ O) {
  // 3 x [ K 24KB (64 x 384B) | V 16KB ] = 120KB -> exactly 1 block/CU
  __shared__ __align__(16) unsigned char SB[3][40960];

  const int tid  = threadIdx.x;
  const int wid  = tid >> 6;      // 0..7
  const int lane = tid & 63;
  const int l31  = lane & 31;
  const int hi   = lane >> 5;
  const int hi16 = hi * 16;
  const int qg   = wid & 3;       // q-group (which 32 q of the 128)
  const int kh   = wid >> 2;      // k-half (which 32 k of the 64-tile)

  const int i  = blockIdx.x;      // 0..255
  const int x  = i & 7;           // XCD
  const int li = i >> 3;          // 0..31
  const int bh = x * 4 + (li >> 3);
  const int jj = li & 7;          // 0..7 -> job pair {15-jj, jj}
  const int b  = bh >> 4, h = bh & 15;

  const char* kg_bh = (const char*)Kg + (size_t)bh * S_ * (DQ_ * 2);
  const char* vg_bh = (const char*)Vg + (size_t)bh * 32 * 16384;

  // lane-constant addressing
  const int kxor = (lane & 7) << 4;
  const int prl  = l31 >> 1;
  const int nb_  = (lane & 1) * 8 + hi;
  int voff[2];
  #pragma unroll
  for (int ks = 0; ks < 2; ++ks) {
    int n = nb_ + kh * 4 + ks * 2;
    voff[ks] = prl * 256 + ((n ^ prl) << 4);
  }

  // staging: 40 x 1KB chunks (K 0..23, V 24..39), 5 per wave; persistent pointers
  #define STAGE(buf)                                                              \
    do {                                                                          \
      _Pragma("unroll")                                                           \
      for (int ci = 0; ci < 5; ++ci) {                                            \
        const int cc = wid * 5 + ci;                                              \
        const char* src = (cc < 24) ? (kSp + ci * 1024) : (vSp + ci * 1024);      \
        GLL16(src, &SB[buf][cc * 1024]);                                          \
      }                                                                           \
      kSp += 24576; vSp += 16384;                                                 \
    } while (0)

  for (int job = 0; job < 2; ++job) {
    const int qt  = job ? jj : (15 - jj);   // 128-row q tile index, 0..15
    const int wq0 = qt * 128 + qg * 32;
    const int qln = wq0 + l31;

    // ---- hoist Q B-fragments (pre-scaled) ----
    short8 qf[12];
    {
      const size_t qoff = (size_t)((b * S_ + qln) * H_ + h) * DQ_;
      #pragma unroll
      for (int d0 = 0; d0 < 12; ++d0) {
        const float* p = Q + qoff + d0 * 16 + hi * 8;
        float4 f0 = *(const float4*)(p);
        float4 f1 = *(const float4*)(p + 4);
        short8 a;
        a[0] = f2bf(f0.x * SCL2); a[1] = f2bf(f0.y * SCL2);
        a[2] = f2bf(f0.z * SCL2); a[3] = f2bf(f0.w * SCL2);
        a[4] = f2bf(f1.x * SCL2); a[5] = f2bf(f1.y * SCL2);
        a[6] = f2bf(f1.z * SCL2); a[7] = f2bf(f1.w * SCL2);
        qf[d0] = a;
      }
    }

    f32x16 o4[4];
    #pragma unroll
    for (int t2 = 0; t2 < 4; ++t2) o4[t2] = (f32x16)0.0f;
    float m = -1e30f, l = 0.0f;

    const int ntiles = 2 * qt + 2;

    // persistent staging pointers (advance one tile per STAGE call)
    const char* kSp = kg_bh + wid * 5120 + lane * 16;
    const char* vSp = vg_bh - 24576 + wid * 5120 + lane * 16;

    // ---- prologue: stage tiles 0 and 1 ----
    STAGE(0);
    if (ntiles > 1) STAGE(1);

    int bc = 0;                            // compute buffer = kt % 3
    for (int kt = 0; kt < ntiles; ++kt) {
      // wait for tile kt (counted: only tile kt+1's 5 chunks may stay in flight)
      if (kt + 1 < ntiles) asm volatile("s_waitcnt vmcnt(5)" ::: "memory");
      else                 asm volatile("s_waitcnt vmcnt(0)" ::: "memory");
      __builtin_amdgcn_s_barrier();
      // stage tile kt+2 into the buffer freed at the barrier ((kt-1)%3)
      if (kt + 2 < ntiles) {
        int bs = bc - 1; if (bs < 0) bs = 2;
        STAGE(bs);
      }

      const int kbase = kt * 64;
      const int khb = kbase + kh * 32;     // this wave's k base

      if (khb <= wq0 + 31) {               // wave-uniform active check
        // ---- QK^T swapped on this wave's 32-k half: 12 MFMAs ----
        const char* kr = (const char*)&SB[bc][0] + (kh * 32 + l31) * 384;
        f32x16 s = (f32x16)0.0f;
        __builtin_amdgcn_s_setprio(1);
        #pragma unroll
        for (int d0 = 0; d0 < 12; ++d0) {
          const int col = (d0 * 32 + hi16) ^ kxor;
          s = __builtin_amdgcn_mfma_f32_32x32x16_bf16(*(const short8*)(kr + col), qf[d0], s, 0, 0, 0);
        }
        __builtin_amdgcn_s_setprio(0);

        // ---- V fragments (latency hides under softmax) ----
        const char* vb = (const char*)&SB[bc][0] + 24576;
        short8 v00 = *(const short8*)(vb + 0 * 4096 + voff[0]);
        short8 v01 = *(const short8*)(vb + 0 * 4096 + voff[1]);
        short8 v10 = *(const short8*)(vb + 1 * 4096 + voff[0]);
        short8 v11 = *(const short8*)(vb + 1 * 4096 + voff[1]);
        short8 v20 = *(const short8*)(vb + 2 * 4096 + voff[0]);
        short8 v21 = *(const short8*)(vb + 2 * 4096 + voff[1]);
        short8 v30 = *(const short8*)(vb + 3 * 4096 + voff[0]);
        short8 v31 = *(const short8*)(vb + 3 * 4096 + voff[1]);

        // ---- mask (only near diagonal) ----
        float p_[16];
        #pragma unroll
        for (int r = 0; r < 16; ++r) p_[r] = s[r];
        if (khb + 31 > wq0) {
          const int rem = qln - khb - 4 * hi;
          #pragma unroll
          for (int r = 0; r < 16; ++r) {
            const int kof = (r & 3) + 8 * (r >> 2);
            if (kof > rem) p_[r] = -1e30f;
          }
        }

        // ---- online softmax (max3 tree: 8 ops for 16 values) ----
        float mA = max3f(max3f(p_[0], p_[1], p_[2]),
                         max3f(p_[3], p_[4], p_[5]),
                         max3f(p_[6], p_[7], p_[8]));
        float mB = max3f(max3f(p_[9], p_[10], p_[11]),
                         max3f(p_[12], p_[13], p_[14]),
                         p_[15]);
        float mx = pl32max(fmaxf(mA, mB));
        if (__any(mx > m + 8.0f)) {        // defer-max
          float mn = fmaxf(m, mx);
          float al = hw_exp2(m - mn);
          #pragma unroll
          for (int t2 = 0; t2 < 4; ++t2) o4[t2] *= al;
          l *= al; m = mn;
        }
        #pragma unroll
        for (int rr = 0; rr < 16; ++rr) p_[rr] = hw_exp2(p_[rr] - m);
        float a8[8];
        #pragma unroll
        for (int r = 0; r < 8; ++r) a8[r] = p_[r] + p_[8 + r];
        float a4[4];
        #pragma unroll
        for (int r = 0; r < 4; ++r) a4[r] = a8[r] + a8[4 + r];
        l += (a4[0] + a4[1]) + (a4[2] + a4[3]);

        // ---- P -> B-fragments: 8 cvtpk + 4 permlane32_swap ----
        unsigned a_ = cvtpk(p_[0], p_[1]),   b2_ = cvtpk(p_[2], p_[3]);
        unsigned c_ = cvtpk(p_[4], p_[5]),   d_  = cvtpk(p_[6], p_[7]);
        unsigned e_ = cvtpk(p_[8], p_[9]),   f_  = cvtpk(p_[10], p_[11]);
        unsigned g_ = cvtpk(p_[12], p_[13]), h_  = cvtpk(p_[14], p_[15]);
        uint2v s02 = __builtin_amdgcn_permlane32_swap(a_, c_, false, false);
        uint2v s13 = __builtin_amdgcn_permlane32_swap(b2_, d_, false, false);
        uint2v s46 = __builtin_amdgcn_permlane32_swap(e_, g_, false, false);
        uint2v s57 = __builtin_amdgcn_permlane32_swap(f_, h_, false, false);
        union { unsigned u[4]; short8 s; } pb0, pb1;
        pb0.u[0] = s02[0]; pb0.u[1] = s13[0]; pb0.u[2] = s02[1]; pb0.u[3] = s13[1];
        pb1.u[0] = s46[0]; pb1.u[1] = s57[0]; pb1.u[2] = s46[1]; pb1.u[3] = s57[1];

        // ---- PV: 8 MFMAs ----
        __builtin_amdgcn_s_setprio(1);
        o4[0] = __builtin_amdgcn_mfma_f32_32x32x16_bf16(v00, pb0.s, o4[0], 0, 0, 0);
        o4[0] = __builtin_amdgcn_mfma_f32_32x32x16_bf16(v01, pb1.s, o4[0], 0, 0, 0);
        o4[1] = __builtin_amdgcn_mfma_f32_32x32x16_bf16(v10, pb0.s, o4[1], 0, 0, 0);
        o4[1] = __builtin_amdgcn_mfma_f32_32x32x16_bf16(v11, pb1.s, o4[1], 0, 0, 0);
        o4[2] = __builtin_amdgcn_mfma_f32_32x32x16_bf16(v20, pb0.s, o4[2], 0, 0, 0);
        o4[2] = __builtin_amdgcn_mfma_f32_32x32x16_bf16(v21, pb1.s, o4[2], 0, 0, 0);
        o4[3] = __builtin_amdgcn_mfma_f32_32x32x16_bf16(v30, pb0.s, o4[3], 0, 0, 0);
        o4[3] = __builtin_amdgcn_mfma_f32_32x32x16_bf16(v31, pb1.s, o4[3], 0, 0, 0);
        __builtin_amdgcn_s_setprio(0);
      }

      ++bc; if (bc == 3) bc = 0;
    }

    // ---- merge the two k-half softmax states, then store ----
    float lr = pl32add(l);
    __syncthreads();                       // all compute reads of SB done
    char* mrg = (char*)&SB[0][0];          // staging dead (vmcnt 0 at last iter)
    if (kh == 1) {
      float* po = (float*)(mrg + qg * 17408 + lane * 272);
      #pragma unroll
      for (int t2 = 0; t2 < 4; ++t2) {
        #pragma unroll
        for (int rr = 0; rr < 4; ++rr) {
          float4 st = { o4[t2][rr * 4 + 0], o4[t2][rr * 4 + 1],
                        o4[t2][rr * 4 + 2], o4[t2][rr * 4 + 3] };
          *(float4*)(po + t2 * 16 + rr * 4) = st;
        }
      }
      float* pm = (float*)(mrg + 69632 + (qg * 64 + lane) * 8);
      pm[0] = m; pm[1] = lr;
    }
    __syncthreads();
    if (kh == 0) {
      const float* po = (const float*)(mrg + qg * 17408 + lane * 272);
      const float* pm = (const float*)(mrg + 69632 + (qg * 64 + lane) * 8);
      const float mB = pm[0], lB = pm[1];
      const float ms = fmaxf(m, mB);
      const float wA = hw_exp2(m - ms), wB = hw_exp2(mB - ms);
      const float inv = 1.0f / (lr * wA + lB * wB);
      float* ob = O + (size_t)((b * S_ + qln) * H_ + h) * DV_;
      #pragma unroll
      for (int t2 = 0; t2 < 4; ++t2) {
        #pragma unroll
        for (int rr = 0; rr < 4; ++rr) {
          float4 vb4 = *(const float4*)(po + t2 * 16 + rr * 4);
          float4 st = { (o4[t2][rr * 4 + 0] * wA + vb4.x * wB) * inv,
                        (o4[t2][rr * 4 + 1] * wA + vb4.y * wB) * inv,
                        (o4[t2][rr * 4 + 2] * wA + vb4.z * wB) * inv,
                        (o4[t2][rr * 4 + 3] * wA + vb4.w * wB) * inv };
          *(float4*)(ob + t2 * 32 + rr * 8 + hi * 4) = st;
        }
      }
    }
    __syncthreads();                       // merge area consumed before next job
  }
  #undef STAGE
}

// ---------------- fallback (no-prep path) if ws too small ----------------
__launch_bounds__(256)
__global__ void mla_fwd_fb(const float* __restrict__ Q,
                           const float* __restrict__ K,
                           const float* __restrict__ V,
                           float* __restrict__ O) {
  __shared__ __align__(16) unsigned short Kl[2][32][200];
  __shared__ __align__(16) unsigned short Vt[2][128][40];
  __shared__ __align__(16) unsigned short Pl[4][16][40];
  const int tid = threadIdx.x, wid = tid >> 6, lane = tid & 63;
  const int l15 = lane & 15, g = lane >> 4;
  const int qtile = (int)gridDim.x - 1 - (int)blockIdx.x;
  const int bh = blockIdx.y, b = bh >> 4, h = bh & 15;
  const int q0w = qtile * 64 + wid * 16;
  const int krs = H_ * DQ_, vrs = H_ * DV_;
  short8 aq[6];
  {
    const int qoff = ((b * S_ + (q0w + l15)) * H_ + h) * DQ_;
    #pragma unroll
    for (int d0 = 0; d0 < 6; ++d0) {
      const float* p = Q + qoff + d0 * 32 + g * 8;
      float4 f0 = *(const float4*)(p); float4 f1 = *(const float4*)(p + 4);
      short8 a;
      a[0]=f2bf(f0.x); a[1]=f2bf(f0.y); a[2]=f2bf(f0.z); a[3]=f2bf(f0.w);
      a[4]=f2bf(f1.x); a[5]=f2bf(f1.y); a[6]=f2bf(f1.z); a[7]=f2bf(f1.w);
      aq[d0] = a;
    }
  }
  f32x4 o[8];
  #pragma unroll
  for (int t = 0; t < 8; ++t) o[t] = (f32x4)0.0f;
  float m[4], l[4];
  #pragma unroll
  for (int r = 0; r < 4; ++r) { m[r] = -1e30f; l[r] = 0.0f; }
  const int ntiles = qtile * 2 + 2;
  float4 kr[6], vr[4];
  {
    const float* Kb = K + ((b * S_) * H_ + h) * DQ_;
    #pragma unroll
    for (int i = 0; i < 6; ++i) { int idx = i*256+tid; int row = idx/48, c4 = idx%48;
      kr[i] = *(const float4*)(Kb + row*krs + c4*4); }
    const float* Vb = V + ((b * S_) * H_ + h) * DV_;
    #pragma unroll
    for (int i = 0; i < 4; ++i) { int idx = i*256+tid; int row = idx&31, c4 = idx>>5;
      vr[i] = *(const float4*)(Vb + row*vrs + c4*4); }
    #pragma unroll
    for (int i = 0; i < 6; ++i) { int idx = i*256+tid; int row = idx/48, c4 = idx%48;
      ushort4 u; u.x=f2bf(kr[i].x); u.y=f2bf(kr[i].y); u.z=f2bf(kr[i].z); u.w=f2bf(kr[i].w);
      *(ushort4*)&Kl[0][row][c4*4] = u; }
    #pragma unroll
    for (int i = 0; i < 4; ++i) { int idx = i*256+tid; int row = idx&31, c4 = idx>>5;
      Vt[0][c4*4+0][row]=f2bf(vr[i].x); Vt[0][c4*4+1][row]=f2bf(vr[i].y);
      Vt[0][c4*4+2][row]=f2bf(vr[i].z); Vt[0][c4*4+3][row]=f2bf(vr[i].w); }
  }
  __syncthreads();
  int cur = 0;
  for (int kt = 0; kt < ntiles; ++kt) {
    const int kbase = kt * 32;
    const bool pf = (kt + 1 < ntiles);
    if (pf) {
      const int nb = kbase + 32;
      const float* Kb = K + ((b*S_+nb)*H_ + h)*DQ_;
      #pragma unroll
      for (int i = 0; i < 6; ++i) { int idx = i*256+tid; int row = idx/48, c4 = idx%48;
        kr[i] = *(const float4*)(Kb + row*krs + c4*4); }
      const float* Vb = V + ((b*S_+nb)*H_ + h)*DV_;
      #pragma unroll
      for (int i = 0; i < 4; ++i) { int idx = i*256+tid; int row = idx&31, c4 = idx>>5;
        vr[i] = *(const float4*)(Vb + row*vrs + c4*4); }
    }
    f32x4 sa0 = (f32x4)0.0f, sa1 = (f32x4)0.0f;
    #pragma unroll
    for (int d0 = 0; d0 < 6; ++d0) {
      short8 b0 = *(const short8*)&Kl[cur][l15][d0*32 + g*8];
      sa0 = __builtin_amdgcn_mfma_f32_16x16x32_bf16(aq[d0], b0, sa0, 0, 0, 0);
      short8 b1 = *(const short8*)&Kl[cur][16+l15][d0*32 + g*8];
      sa1 = __builtin_amdgcn_mfma_f32_16x16x32_bf16(aq[d0], b1, sa1, 0, 0, 0);
    }
    float p0[4], p1[4];
    #pragma unroll
    for (int r = 0; r < 4; ++r) {
      const int qg = q0w + 4*g + r;
      float s0 = sa0[r]*SCL2, s1 = sa1[r]*SCL2;
      if (kbase + l15 > qg) s0 = -1e30f;
      if (kbase + 16 + l15 > qg) s1 = -1e30f;
      p0[r] = s0; p1[r] = s1;
    }
    #pragma unroll
    for (int r = 0; r < 4; ++r) {
      float rm = fmaxf(p0[r], p1[r]);
      #pragma unroll
      for (int off = 1; off < 16; off <<= 1) rm = fmaxf(rm, __shfl_xor(rm, off));
      float mn = fmaxf(m[r], rm);
      float alpha = exp2f(m[r] - mn); m[r] = mn;
      float e0 = exp2f(p0[r] - mn), e1 = exp2f(p1[r] - mn);
      p0[r] = e0; p1[r] = e1;
      float rsum = e0 + e1;
      #pragma unroll
      for (int off = 1; off < 16; off <<= 1) rsum += __shfl_xor(rsum, off);
      l[r] = l[r]*alpha + rsum;
      #pragma unroll
      for (int t = 0; t < 8; ++t) o[t][r] *= alpha;
    }
    #pragma unroll
    for (int r = 0; r < 4; ++r) {
      Pl[wid][4*g+r][l15]      = f2bf(p0[r]);
      Pl[wid][4*g+r][16+l15]   = f2bf(p1[r]);
    }
    short8 pa = *(const short8*)&Pl[wid][l15][g*8];
    #pragma unroll
    for (int t = 0; t < 8; ++t) {
      short8 vb = *(const short8*)&Vt[cur][t*16+l15][g*8];
      o[t] = __builtin_amdgcn_mfma_f32_16x16x32_bf16(pa, vb, o[t], 0, 0, 0);
    }
    if (pf) {
      #pragma unroll
      for (int i = 0; i < 6; ++i) { int idx = i*256+tid; int row = idx/48, c4 = idx%48;
        ushort4 u; u.x=f2bf(kr[i].x); u.y=f2bf(kr[i].y); u.z=f2bf(kr[i].z); u.w=f2bf(kr[i].w);
        *(ushort4*)&Kl[cur^1][row][c4*4] = u; }
      #pragma unroll
      for (int i = 0; i < 4; ++i) { int idx = i*256+tid; int row = idx&31, c4 = idx>>5;
        Vt[cur^1][c4*4+0][row]=f2bf(vr[i].x); Vt[cur^1][c4*4+1][row]=f2bf(vr[i].y);
        Vt[cur^1][c4*4+2][row]=f2bf(vr[i].z); Vt[cur^1][c4*4+3][row]=f2bf(vr[i].w); }
    }
    __syncthreads();
    cur ^= 1;
  }
  #pragma unroll
  for (int r = 0; r < 4; ++r) {
    const int qg = q0w + 4*g + r;
    const float inv = 1.0f / l[r];
    #pragma unroll
    for (int t = 0; t < 8; ++t)
      O[((b*S_+qg)*H_ + h)*DV_ + t*16 + l15] = o[t][r] * inv;
  }
}

extern "C" void kernel_launch(void* const* d_in, const int* in_sizes, int n_in,
                              void* d_out, int out_size, void* d_ws, size_t ws_size,
                              hipStream_t stream) {
  const float* q = (const float*)d_in[0];
  const float* k = (const float*)d_in[1];
  const float* v = (const float*)d_in[2];
  float* out = (float*)d_out;

  if (ws_size >= KG_BYTES + VG_BYTES) {
    unsigned short* Kg = (unsigned short*)d_ws;
    unsigned short* Vg = (unsigned short*)((char*)d_ws + KG_BYTES);
    prep_kv<<<dim3(12288 + B_ * H_ * 32), dim3(256), 0, stream>>>(k, v, Kg, Vg);
    mla_fwd<<<dim3(256), dim3(512), 0, stream>>>(q, Kg, Vg, out);
  } else {
    dim3 grid(S_ / 64, B_ * H_);
    mla_fwd_fb<<<grid, dim3(256), 0, stream>>>(q, k, v, out);
  }
}